// Round 1
// baseline (3228.856 us; speedup 1.0000x reference)
//
#include <hip/hip_runtime.h>
#include <math.h>

#define NGRAPHS 256
#define PD_EPS 1e-6f

static __device__ __forceinline__ int wave_uniform(int v) {
  return __builtin_amdgcn_readfirstlane(v);
}

// ---------- degree count over dst ----------
__global__ void k_count(const int* __restrict__ dst, int* __restrict__ cnt, int E) {
  int e = blockIdx.x * blockDim.x + threadIdx.x;
  if (e < E) atomicAdd(&cnt[dst[e]], 1);
}

// ---------- 3-phase exclusive scan (N=100k) ----------
__global__ void k_scan1(const int* __restrict__ cnt, int* __restrict__ off,
                        int* __restrict__ bsums, int n) {
  __shared__ int s[256];
  int tid = threadIdx.x;
  int gid = blockIdx.x * 256 + tid;
  int v = (gid < n) ? cnt[gid] : 0;
  s[tid] = v; __syncthreads();
  for (int o = 1; o < 256; o <<= 1) {
    int t = (tid >= o) ? s[tid - o] : 0;
    __syncthreads();
    s[tid] += t;
    __syncthreads();
  }
  if (gid < n) off[gid] = s[tid] - v;          // local exclusive
  if (tid == 255) bsums[blockIdx.x] = s[255];  // block total
}

__global__ void k_scan2(int* __restrict__ bsums, int nb) {
  __shared__ int s[512];
  int tid = threadIdx.x;
  int v = (tid < nb) ? bsums[tid] : 0;
  s[tid] = v; __syncthreads();
  for (int o = 1; o < 512; o <<= 1) {
    int t = (tid >= o) ? s[tid - o] : 0;
    __syncthreads();
    s[tid] += t;
    __syncthreads();
  }
  if (tid < nb) bsums[tid] = s[tid] - v;       // exclusive
}

__global__ void k_finalize(int* __restrict__ off, const int* __restrict__ bsums,
                           int* __restrict__ cursor, const int* __restrict__ cnt,
                           float* __restrict__ dinv, int n, int E) {
  int gid = blockIdx.x * 256 + threadIdx.x;
  if (gid < n) {
    int o = off[gid] + bsums[blockIdx.x];
    off[gid] = o;
    cursor[gid] = o;
    // deg includes the self-loop; deg >= 1 always -> dinv = 1/sqrt(deg)
    dinv[gid] = 1.0f / sqrtf((float)(cnt[gid] + 1));
  }
  if (gid == 0) off[n] = E;
}

// ---------- CSR fill (counting sort by dst; intra-node order irrelevant) ----------
__global__ void k_fill(const int* __restrict__ src, const int* __restrict__ dst,
                       int* __restrict__ cursor, int* __restrict__ csr, int E) {
  int e = blockIdx.x * blockDim.x + threadIdx.x;
  if (e < E) {
    int p = atomicAdd(&cursor[dst[e]], 1);
    csr[p] = src[e];
  }
}

// ---------- GEMM fused with dinv scale: out[n,f] = dinv[n] * (in[n,:] @ W[:,f]) ----------
// One wave per node; lane = output feature; W column in VGPRs; x row via
// wave-uniform float4 broadcast loads (scalar path after readfirstlane).
template <int K>
__global__ __launch_bounds__(256) void k_gemm(const float* __restrict__ in,
                                              const float* __restrict__ Wg,
                                              const float* __restrict__ dinv,
                                              float* __restrict__ out, int n) {
  int lane = threadIdx.x & 63;
  int wid = (blockIdx.x * blockDim.x + threadIdx.x) >> 6;
  int nw = (gridDim.x * blockDim.x) >> 6;
  float w[K];
#pragma unroll
  for (int j = 0; j < K; ++j) w[j] = Wg[j * 64 + lane];
  for (int node = wid; node < n; node += nw) {
    int un = wave_uniform(node);
    const float* xr = in + (size_t)un * K;
    float acc = 0.f;
#pragma unroll 8
    for (int j4 = 0; j4 < K / 4; ++j4) {
      float4 xv = *(const float4*)(xr + 4 * j4);
      acc = fmaf(xv.x, w[4 * j4 + 0], acc);
      acc = fmaf(xv.y, w[4 * j4 + 1], acc);
      acc = fmaf(xv.z, w[4 * j4 + 2], acc);
      acc = fmaf(xv.w, w[4 * j4 + 3], acc);
    }
    out[(size_t)un * 64 + lane] = acc * dinv[un];
  }
}

// ---------- aggregate: out[d] = act(dinv[d]*(sum_{s in N(d)} h'[s] + h'[d]) + b) ----------
__global__ __launch_bounds__(256) void k_agg(const float* __restrict__ hp,
                                             const int* __restrict__ off,
                                             const int* __restrict__ csr,
                                             const float* __restrict__ dinv,
                                             const float* __restrict__ bias,
                                             float* __restrict__ out, int n,
                                             int do_relu) {
  int lane = threadIdx.x & 63;
  int wid = (blockIdx.x * blockDim.x + threadIdx.x) >> 6;
  int nw = (gridDim.x * blockDim.x) >> 6;
  float b = bias[lane];
  for (int node = wid; node < n; node += nw) {
    int un = wave_uniform(node);
    int beg = off[un], end = off[un + 1];
    float acc = hp[(size_t)un * 64 + lane];  // self-loop term
    int e = beg;
    for (; e + 4 <= end; e += 4) {
      int s0 = csr[e + 0];
      int s1 = csr[e + 1];
      int s2 = csr[e + 2];
      int s3 = csr[e + 3];
      float a0 = hp[(size_t)s0 * 64 + lane];
      float a1 = hp[(size_t)s1 * 64 + lane];
      float a2 = hp[(size_t)s2 * 64 + lane];
      float a3 = hp[(size_t)s3 * 64 + lane];
      acc += a0 + a1 + a2 + a3;
    }
    for (; e < end; ++e) {
      int s = csr[e];
      acc += hp[(size_t)s * 64 + lane];
    }
    float v = fmaf(acc, dinv[un], b);
    if (do_relu) v = fmaxf(v, 0.f);
    out[(size_t)un * 64 + lane] = v;
  }
}

// ---------- mean-pool accumulate (batch sorted; atomics into [G,64]) ----------
__global__ void k_pool(const float* __restrict__ x3, const int* __restrict__ batch,
                       float* __restrict__ pooled, float* __restrict__ cnt, int n) {
  int node = (int)((blockIdx.x * (size_t)blockDim.x + threadIdx.x) >> 6);
  int lane = threadIdx.x & 63;
  if (node < n) {
    int g = batch[node];
    atomicAdd(&pooled[g * 64 + lane], x3[(size_t)node * 64 + lane]);
    if (lane == 0) atomicAdd(&cnt[g], 1.0f);
  }
}

// ---------- head: e = (pool/cnt)@Wlin + blin for both towers, L2 distance ----------
__global__ void k_final(const float* __restrict__ pooled1, const float* __restrict__ cnt1,
                        const float* __restrict__ pooled2, const float* __restrict__ cnt2,
                        const float* __restrict__ Wlin, const float* __restrict__ blin,
                        float* __restrict__ outp) {
  int g = blockIdx.x;
  int lane = threadIdx.x;  // 64 threads
  float c1 = fmaxf(cnt1[g], 1.f), c2 = fmaxf(cnt2[g], 1.f);
  float p1 = pooled1[g * 64 + lane] / c1;
  float p2 = pooled2[g * 64 + lane] / c2;
  float e1 = blin[lane], e2 = blin[lane];
  for (int j = 0; j < 64; ++j) {
    float w = Wlin[j * 64 + lane];
    e1 = fmaf(__shfl(p1, j), w, e1);
    e2 = fmaf(__shfl(p2, j), w, e2);
  }
  float d = e1 - e2 + PD_EPS;
  float sq = d * d;
  for (int o = 32; o > 0; o >>= 1) sq += __shfl_down(sq, o);
  if (lane == 0) outp[g] = sqrtf(sq);
}

extern "C" void kernel_launch(void* const* d_in, const int* in_sizes, int n_in,
                              void* d_out, int out_size, void* d_ws, size_t ws_size,
                              hipStream_t stream) {
  const float* x1 = (const float*)d_in[0];
  const int* ei1 = (const int*)d_in[1];
  const int* batch1 = (const int*)d_in[2];
  const float* x2 = (const float*)d_in[3];
  const int* ei2 = (const int*)d_in[4];
  const int* batch2 = (const int*)d_in[5];
  const float* W1 = (const float*)d_in[6];
  const float* b1 = (const float*)d_in[7];
  const float* W2 = (const float*)d_in[8];
  const float* b2 = (const float*)d_in[9];
  const float* W3 = (const float*)d_in[10];
  const float* b3 = (const float*)d_in[11];
  const float* Wlin = (const float*)d_in[12];
  const float* blin = (const float*)d_in[13];

  const int N = in_sizes[2];      // 100000
  const int E = in_sizes[1] / 2;  // 1600000

  // workspace carve (~60 MB)
  char* p = (char*)d_ws;
  auto alloc = [&](size_t bytes) {
    char* r = p;
    p += (bytes + 255) & ~(size_t)255;
    return r;
  };
  int* off = (int*)alloc((size_t)(N + 1) * 4);
  int* cntdeg = (int*)alloc((size_t)N * 4);
  int* cursor = (int*)alloc((size_t)N * 4);
  int* bsums = (int*)alloc(512 * 4);
  float* dinv = (float*)alloc((size_t)N * 4);
  int* csr = (int*)alloc((size_t)E * 4);
  float* bufA = (float*)alloc((size_t)N * 64 * 4);
  float* bufB = (float*)alloc((size_t)N * 64 * 4);
  float* pooled1 = (float*)alloc((size_t)NGRAPHS * 64 * 4);
  float* cnt1 = (float*)alloc((size_t)NGRAPHS * 4);
  float* pooled2 = (float*)alloc((size_t)NGRAPHS * 64 * 4);
  float* cnt2 = (float*)alloc((size_t)NGRAPHS * 4);

  const int nbN = (N + 255) / 256;
  const int nbE = (E + 255) / 256;

  for (int t = 0; t < 2; ++t) {
    const float* x = t ? x2 : x1;
    const int* src = t ? ei2 : ei1;
    const int* dst = src + E;
    const int* batch = t ? batch2 : batch1;
    float* pooled = t ? pooled2 : pooled1;
    float* cnt = t ? cnt2 : cnt1;

    hipMemsetAsync(cntdeg, 0, (size_t)N * 4, stream);
    hipMemsetAsync(pooled, 0, (size_t)NGRAPHS * 64 * 4, stream);
    hipMemsetAsync(cnt, 0, (size_t)NGRAPHS * 4, stream);

    k_count<<<nbE, 256, 0, stream>>>(dst, cntdeg, E);
    k_scan1<<<nbN, 256, 0, stream>>>(cntdeg, off, bsums, N);
    k_scan2<<<1, 512, 0, stream>>>(bsums, nbN);
    k_finalize<<<nbN, 256, 0, stream>>>(off, bsums, cursor, cntdeg, dinv, N, E);
    k_fill<<<nbE, 256, 0, stream>>>(src, dst, cursor, csr, E);

    // layer 1: x[N,128] -> bufB
    k_gemm<128><<<1024, 256, 0, stream>>>(x, W1, dinv, bufA, N);
    k_agg<<<2048, 256, 0, stream>>>(bufA, off, csr, dinv, b1, bufB, N, 1);
    // layer 2
    k_gemm<64><<<1024, 256, 0, stream>>>(bufB, W2, dinv, bufA, N);
    k_agg<<<2048, 256, 0, stream>>>(bufA, off, csr, dinv, b2, bufB, N, 1);
    // layer 3 (no relu)
    k_gemm<64><<<1024, 256, 0, stream>>>(bufB, W3, dinv, bufA, N);
    k_agg<<<2048, 256, 0, stream>>>(bufA, off, csr, dinv, b3, bufB, N, 0);

    k_pool<<<(int)(((size_t)N * 64 + 255) / 256), 256, 0, stream>>>(bufB, batch, pooled,
                                                                    cnt, N);
  }
  k_final<<<NGRAPHS, 64, 0, stream>>>(pooled1, cnt1, pooled2, cnt2, Wlin, blin,
                                      (float*)d_out);
}

// Round 2
// 1927.064 us; speedup vs baseline: 1.6755x; 1.6755x over previous
//
#include <hip/hip_runtime.h>
#include <math.h>

#define NGRAPHS 256
#define PD_EPS 1e-6f

static __device__ __forceinline__ int wave_uniform(int v) {
  return __builtin_amdgcn_readfirstlane(v);
}

// ---------- degree count over dst ----------
__global__ void k_count(const int* __restrict__ dst, int* __restrict__ cnt, int E) {
  int e = blockIdx.x * blockDim.x + threadIdx.x;
  if (e < E) atomicAdd(&cnt[dst[e]], 1);
}

// ---------- 3-phase exclusive scan (N=100k) ----------
__global__ void k_scan1(const int* __restrict__ cnt, int* __restrict__ off,
                        int* __restrict__ bsums, int n) {
  __shared__ int s[256];
  int tid = threadIdx.x;
  int gid = blockIdx.x * 256 + tid;
  int v = (gid < n) ? cnt[gid] : 0;
  s[tid] = v; __syncthreads();
  for (int o = 1; o < 256; o <<= 1) {
    int t = (tid >= o) ? s[tid - o] : 0;
    __syncthreads();
    s[tid] += t;
    __syncthreads();
  }
  if (gid < n) off[gid] = s[tid] - v;          // local exclusive
  if (tid == 255) bsums[blockIdx.x] = s[255];  // block total
}

__global__ void k_scan2(int* __restrict__ bsums, int nb) {
  __shared__ int s[512];
  int tid = threadIdx.x;
  int v = (tid < nb) ? bsums[tid] : 0;
  s[tid] = v; __syncthreads();
  for (int o = 1; o < 512; o <<= 1) {
    int t = (tid >= o) ? s[tid - o] : 0;
    __syncthreads();
    s[tid] += t;
    __syncthreads();
  }
  if (tid < nb) bsums[tid] = s[tid] - v;       // exclusive
}

__global__ void k_finalize(int* __restrict__ off, const int* __restrict__ bsums,
                           int* __restrict__ cursor, const int* __restrict__ cnt,
                           float* __restrict__ dinv, int n, int E) {
  int gid = blockIdx.x * 256 + threadIdx.x;
  if (gid < n) {
    int o = off[gid] + bsums[blockIdx.x];
    off[gid] = o;
    cursor[gid] = o;
    // deg includes the self-loop; deg >= 1 always -> dinv = 1/sqrt(deg)
    dinv[gid] = 1.0f / sqrtf((float)(cnt[gid] + 1));
  }
  if (gid == 0) off[n] = E;
}

// ---------- CSR fill (counting sort by dst; intra-node order irrelevant) ----------
__global__ void k_fill(const int* __restrict__ src, const int* __restrict__ dst,
                       int* __restrict__ cursor, int* __restrict__ csr, int E) {
  int e = blockIdx.x * blockDim.x + threadIdx.x;
  if (e < E) {
    int p = atomicAdd(&cursor[dst[e]], 1);
    csr[p] = src[e];
  }
}

// ---------- GEMM fused with dinv scale: out[n,f] = dinv[n] * (in[n,:] @ W[:,f]) ----------
// One wave per node; lane = output feature; W column held in VGPRs.
// CRITICAL: the K-loop must be FULLY unrolled — a partial unroll leaves a
// runtime index into w[] and the compiler demotes the array to scratch
// (R1 profile: VGPR_Count=20, 157 MB spill writes, 1.7 GB spill reads).
// x row is wave-uniform (readfirstlane'd node) -> scalar-path loads.
template <int K>
__global__ __launch_bounds__(256, 1) void k_gemm(const float* __restrict__ in,
                                                 const float* __restrict__ Wg,
                                                 const float* __restrict__ dinv,
                                                 float* __restrict__ out, int n) {
  int lane = threadIdx.x & 63;
  int wid = (blockIdx.x * blockDim.x + threadIdx.x) >> 6;
  int nw = (gridDim.x * blockDim.x) >> 6;
  float w[K];
#pragma unroll
  for (int j = 0; j < K; ++j) w[j] = Wg[j * 64 + lane];
  for (int node = wid; node < n; node += nw) {
    int un = wave_uniform(node);
    const float* xr = in + (size_t)un * K;
    float acc = 0.f;
#pragma unroll
    for (int j4 = 0; j4 < K / 4; ++j4) {
      float4 xv = *(const float4*)(xr + 4 * j4);
      acc = fmaf(xv.x, w[4 * j4 + 0], acc);
      acc = fmaf(xv.y, w[4 * j4 + 1], acc);
      acc = fmaf(xv.z, w[4 * j4 + 2], acc);
      acc = fmaf(xv.w, w[4 * j4 + 3], acc);
    }
    out[(size_t)un * 64 + lane] = acc * dinv[un];
  }
}

// ---------- aggregate: out[d] = act(dinv[d]*(sum_{s in N(d)} h'[s] + h'[d]) + b) ----------
__global__ __launch_bounds__(256) void k_agg(const float* __restrict__ hp,
                                             const int* __restrict__ off,
                                             const int* __restrict__ csr,
                                             const float* __restrict__ dinv,
                                             const float* __restrict__ bias,
                                             float* __restrict__ out, int n,
                                             int do_relu) {
  int lane = threadIdx.x & 63;
  int wid = (blockIdx.x * blockDim.x + threadIdx.x) >> 6;
  int nw = (gridDim.x * blockDim.x) >> 6;
  float b = bias[lane];
  for (int node = wid; node < n; node += nw) {
    int un = wave_uniform(node);
    int beg = off[un], end = off[un + 1];
    float acc = hp[(size_t)un * 64 + lane];  // self-loop term
    int e = beg;
    for (; e + 4 <= end; e += 4) {
      int s0 = csr[e + 0];
      int s1 = csr[e + 1];
      int s2 = csr[e + 2];
      int s3 = csr[e + 3];
      float a0 = hp[(size_t)s0 * 64 + lane];
      float a1 = hp[(size_t)s1 * 64 + lane];
      float a2 = hp[(size_t)s2 * 64 + lane];
      float a3 = hp[(size_t)s3 * 64 + lane];
      acc += a0 + a1 + a2 + a3;
    }
    for (; e < end; ++e) {
      int s = csr[e];
      acc += hp[(size_t)s * 64 + lane];
    }
    float v = fmaf(acc, dinv[un], b);
    if (do_relu) v = fmaxf(v, 0.f);
    out[(size_t)un * 64 + lane] = v;
  }
}

// ---------- mean-pool accumulate (batch sorted; atomics into [G,64]) ----------
__global__ void k_pool(const float* __restrict__ x3, const int* __restrict__ batch,
                       float* __restrict__ pooled, float* __restrict__ cnt, int n) {
  int node = (int)((blockIdx.x * (size_t)blockDim.x + threadIdx.x) >> 6);
  int lane = threadIdx.x & 63;
  if (node < n) {
    int g = batch[node];
    atomicAdd(&pooled[g * 64 + lane], x3[(size_t)node * 64 + lane]);
    if (lane == 0) atomicAdd(&cnt[g], 1.0f);
  }
}

// ---------- head: e = (pool/cnt)@Wlin + blin for both towers, L2 distance ----------
__global__ void k_final(const float* __restrict__ pooled1, const float* __restrict__ cnt1,
                        const float* __restrict__ pooled2, const float* __restrict__ cnt2,
                        const float* __restrict__ Wlin, const float* __restrict__ blin,
                        float* __restrict__ outp) {
  int g = blockIdx.x;
  int lane = threadIdx.x;  // 64 threads
  float c1 = fmaxf(cnt1[g], 1.f), c2 = fmaxf(cnt2[g], 1.f);
  float p1 = pooled1[g * 64 + lane] / c1;
  float p2 = pooled2[g * 64 + lane] / c2;
  float e1 = blin[lane], e2 = blin[lane];
  for (int j = 0; j < 64; ++j) {
    float w = Wlin[j * 64 + lane];
    e1 = fmaf(__shfl(p1, j), w, e1);
    e2 = fmaf(__shfl(p2, j), w, e2);
  }
  float d = e1 - e2 + PD_EPS;
  float sq = d * d;
  for (int o = 32; o > 0; o >>= 1) sq += __shfl_down(sq, o);
  if (lane == 0) outp[g] = sqrtf(sq);
}

extern "C" void kernel_launch(void* const* d_in, const int* in_sizes, int n_in,
                              void* d_out, int out_size, void* d_ws, size_t ws_size,
                              hipStream_t stream) {
  const float* x1 = (const float*)d_in[0];
  const int* ei1 = (const int*)d_in[1];
  const int* batch1 = (const int*)d_in[2];
  const float* x2 = (const float*)d_in[3];
  const int* ei2 = (const int*)d_in[4];
  const int* batch2 = (const int*)d_in[5];
  const float* W1 = (const float*)d_in[6];
  const float* b1 = (const float*)d_in[7];
  const float* W2 = (const float*)d_in[8];
  const float* b2 = (const float*)d_in[9];
  const float* W3 = (const float*)d_in[10];
  const float* b3 = (const float*)d_in[11];
  const float* Wlin = (const float*)d_in[12];
  const float* blin = (const float*)d_in[13];

  const int N = in_sizes[2];      // 100000
  const int E = in_sizes[1] / 2;  // 1600000

  // workspace carve (~60 MB)
  char* p = (char*)d_ws;
  auto alloc = [&](size_t bytes) {
    char* r = p;
    p += (bytes + 255) & ~(size_t)255;
    return r;
  };
  int* off = (int*)alloc((size_t)(N + 1) * 4);
  int* cntdeg = (int*)alloc((size_t)N * 4);
  int* cursor = (int*)alloc((size_t)N * 4);
  int* bsums = (int*)alloc(512 * 4);
  float* dinv = (float*)alloc((size_t)N * 4);
  int* csr = (int*)alloc((size_t)E * 4);
  float* bufA = (float*)alloc((size_t)N * 64 * 4);
  float* bufB = (float*)alloc((size_t)N * 64 * 4);
  float* pooled1 = (float*)alloc((size_t)NGRAPHS * 64 * 4);
  float* cnt1 = (float*)alloc((size_t)NGRAPHS * 4);
  float* pooled2 = (float*)alloc((size_t)NGRAPHS * 64 * 4);
  float* cnt2 = (float*)alloc((size_t)NGRAPHS * 4);

  const int nbN = (N + 255) / 256;
  const int nbE = (E + 255) / 256;

  for (int t = 0; t < 2; ++t) {
    const float* x = t ? x2 : x1;
    const int* src = t ? ei2 : ei1;
    const int* dst = src + E;
    const int* batch = t ? batch2 : batch1;
    float* pooled = t ? pooled2 : pooled1;
    float* cnt = t ? cnt2 : cnt1;

    hipMemsetAsync(cntdeg, 0, (size_t)N * 4, stream);
    hipMemsetAsync(pooled, 0, (size_t)NGRAPHS * 64 * 4, stream);
    hipMemsetAsync(cnt, 0, (size_t)NGRAPHS * 4, stream);

    k_count<<<nbE, 256, 0, stream>>>(dst, cntdeg, E);
    k_scan1<<<nbN, 256, 0, stream>>>(cntdeg, off, bsums, N);
    k_scan2<<<1, 512, 0, stream>>>(bsums, nbN);
    k_finalize<<<nbN, 256, 0, stream>>>(off, bsums, cursor, cntdeg, dinv, N, E);
    k_fill<<<nbE, 256, 0, stream>>>(src, dst, cursor, csr, E);

    // layer 1: x[N,128] -> bufB
    k_gemm<128><<<1024, 256, 0, stream>>>(x, W1, dinv, bufA, N);
    k_agg<<<2048, 256, 0, stream>>>(bufA, off, csr, dinv, b1, bufB, N, 1);
    // layer 2
    k_gemm<64><<<1024, 256, 0, stream>>>(bufB, W2, dinv, bufA, N);
    k_agg<<<2048, 256, 0, stream>>>(bufA, off, csr, dinv, b2, bufB, N, 1);
    // layer 3 (no relu)
    k_gemm<64><<<1024, 256, 0, stream>>>(bufB, W3, dinv, bufA, N);
    k_agg<<<2048, 256, 0, stream>>>(bufA, off, csr, dinv, b3, bufB, N, 0);

    k_pool<<<(int)(((size_t)N * 64 + 255) / 256), 256, 0, stream>>>(bufB, batch, pooled,
                                                                    cnt, N);
  }
  k_final<<<NGRAPHS, 64, 0, stream>>>(pooled1, cnt1, pooled2, cnt2, Wlin, blin,
                                      (float*)d_out);
}

// Round 3
// 1253.395 us; speedup vs baseline: 2.5761x; 1.5375x over previous
//
#include <hip/hip_runtime.h>
#include <math.h>

#define NGRAPHS 256
#define PD_EPS 1e-6f
#define POOL_CHUNK 64

static __device__ __forceinline__ int wave_uniform(int v) {
  return __builtin_amdgcn_readfirstlane(v);
}

// ---------- degree count over dst ----------
__global__ void k_count(const int* __restrict__ dst, int* __restrict__ cnt, int E) {
  int e = blockIdx.x * blockDim.x + threadIdx.x;
  if (e < E) atomicAdd(&cnt[dst[e]], 1);
}

// ---------- 3-phase exclusive scan (N=100k) ----------
__global__ void k_scan1(const int* __restrict__ cnt, int* __restrict__ off,
                        int* __restrict__ bsums, int n) {
  __shared__ int s[256];
  int tid = threadIdx.x;
  int gid = blockIdx.x * 256 + tid;
  int v = (gid < n) ? cnt[gid] : 0;
  s[tid] = v; __syncthreads();
  for (int o = 1; o < 256; o <<= 1) {
    int t = (tid >= o) ? s[tid - o] : 0;
    __syncthreads();
    s[tid] += t;
    __syncthreads();
  }
  if (gid < n) off[gid] = s[tid] - v;          // local exclusive
  if (tid == 255) bsums[blockIdx.x] = s[255];  // block total
}

__global__ void k_scan2(int* __restrict__ bsums, int nb) {
  __shared__ int s[512];
  int tid = threadIdx.x;
  int v = (tid < nb) ? bsums[tid] : 0;
  s[tid] = v; __syncthreads();
  for (int o = 1; o < 512; o <<= 1) {
    int t = (tid >= o) ? s[tid - o] : 0;
    __syncthreads();
    s[tid] += t;
    __syncthreads();
  }
  if (tid < nb) bsums[tid] = s[tid] - v;       // exclusive
}

__global__ void k_finalize(int* __restrict__ off, const int* __restrict__ bsums,
                           int* __restrict__ cursor, const int* __restrict__ cnt,
                           float* __restrict__ dinv, int n, int E) {
  int gid = blockIdx.x * 256 + threadIdx.x;
  if (gid < n) {
    int o = off[gid] + bsums[blockIdx.x];
    off[gid] = o;
    cursor[gid] = o;
    // deg includes the self-loop; deg >= 1 always -> dinv = 1/sqrt(deg)
    dinv[gid] = 1.0f / sqrtf((float)(cnt[gid] + 1));
  }
  if (gid == 0) off[n] = E;
}

// ---------- CSR fill (counting sort by dst; intra-node order irrelevant) ----------
__global__ void k_fill(const int* __restrict__ src, const int* __restrict__ dst,
                       int* __restrict__ cursor, int* __restrict__ csr, int E) {
  int e = blockIdx.x * blockDim.x + threadIdx.x;
  if (e < E) {
    int p = atomicAdd(&cursor[dst[e]], 1);
    csr[p] = src[e];
  }
}

// ---------- GEMM fused with dinv scale: out[n,f] = dinv[n] * (in[n,:] @ W[:,f]) ----------
// One wave per node; lane = output feature; W column held in VGPRs.
// CRITICAL: the K-loop must be FULLY unrolled — a partial unroll leaves a
// runtime index into w[] and the compiler demotes the array to scratch
// (R1 profile: VGPR_Count=20, 157 MB spill writes, 1.7 GB spill reads).
// x row is wave-uniform (readfirstlane'd node) -> scalar-path loads.
template <int K>
__global__ __launch_bounds__(256, 1) void k_gemm(const float* __restrict__ in,
                                                 const float* __restrict__ Wg,
                                                 const float* __restrict__ dinv,
                                                 float* __restrict__ out, int n) {
  int lane = threadIdx.x & 63;
  int wid = (blockIdx.x * blockDim.x + threadIdx.x) >> 6;
  int nw = (gridDim.x * blockDim.x) >> 6;
  float w[K];
#pragma unroll
  for (int j = 0; j < K; ++j) w[j] = Wg[j * 64 + lane];
  for (int node = wid; node < n; node += nw) {
    int un = wave_uniform(node);
    const float* xr = in + (size_t)un * K;
    float acc = 0.f;
#pragma unroll
    for (int j4 = 0; j4 < K / 4; ++j4) {
      float4 xv = *(const float4*)(xr + 4 * j4);
      acc = fmaf(xv.x, w[4 * j4 + 0], acc);
      acc = fmaf(xv.y, w[4 * j4 + 1], acc);
      acc = fmaf(xv.z, w[4 * j4 + 2], acc);
      acc = fmaf(xv.w, w[4 * j4 + 3], acc);
    }
    out[(size_t)un * 64 + lane] = acc * dinv[un];
  }
}

// ---------- aggregate: out[d] = act(dinv[d]*(sum_{s in N(d)} h'[s] + h'[d]) + b) ----------
__global__ __launch_bounds__(256) void k_agg(const float* __restrict__ hp,
                                             const int* __restrict__ off,
                                             const int* __restrict__ csr,
                                             const float* __restrict__ dinv,
                                             const float* __restrict__ bias,
                                             float* __restrict__ out, int n,
                                             int do_relu) {
  int lane = threadIdx.x & 63;
  int wid = (blockIdx.x * blockDim.x + threadIdx.x) >> 6;
  int nw = (gridDim.x * blockDim.x) >> 6;
  float b = bias[lane];
  for (int node = wid; node < n; node += nw) {
    int un = wave_uniform(node);
    int beg = off[un], end = off[un + 1];
    float acc = hp[(size_t)un * 64 + lane];  // self-loop term
    int e = beg;
    for (; e + 4 <= end; e += 4) {
      int s0 = csr[e + 0];
      int s1 = csr[e + 1];
      int s2 = csr[e + 2];
      int s3 = csr[e + 3];
      float a0 = hp[(size_t)s0 * 64 + lane];
      float a1 = hp[(size_t)s1 * 64 + lane];
      float a2 = hp[(size_t)s2 * 64 + lane];
      float a3 = hp[(size_t)s3 * 64 + lane];
      acc += a0 + a1 + a2 + a3;
    }
    for (; e < end; ++e) {
      int s = csr[e];
      acc += hp[(size_t)s * 64 + lane];
    }
    float v = fmaf(acc, dinv[un], b);
    if (do_relu) v = fmaxf(v, 0.f);
    out[(size_t)un * 64 + lane] = v;
  }
}

// ---------- mean-pool: segment-reduce over sorted batch ----------
// One wave per POOL_CHUNK contiguous nodes; lane = feature. Accumulate the
// segment sum in a register while the (wave-uniform) graph id is unchanged;
// one atomicAdd per graph boundary. R2 profile: per-node atomics were 403 us
// (6.4M atomics on 64 KB); this emits ~2 boundary flushes per wave.
__global__ __launch_bounds__(256) void k_pool(const float* __restrict__ x3,
                                              const int* __restrict__ batch,
                                              float* __restrict__ pooled,
                                              float* __restrict__ cnt, int n) {
  int lane = threadIdx.x & 63;
  int wid = (blockIdx.x * blockDim.x + threadIdx.x) >> 6;
  int beg = wid * POOL_CHUNK;
  if (beg >= n) return;
  int end = beg + POOL_CHUNK;
  if (end > n) end = n;

  int cur = wave_uniform(batch[beg]);
  float acc = 0.f;
  int cl = 0;
  int i = beg;
  for (; i + 4 <= end; i += 4) {
    int g0 = wave_uniform(batch[i + 0]);
    int g3 = wave_uniform(batch[i + 3]);
    float a0 = x3[(size_t)(i + 0) * 64 + lane];
    float a1 = x3[(size_t)(i + 1) * 64 + lane];
    float a2 = x3[(size_t)(i + 2) * 64 + lane];
    float a3 = x3[(size_t)(i + 3) * 64 + lane];
    if (g0 == cur && g3 == cur) {  // sorted => all 4 in current segment
      acc += a0 + a1 + a2 + a3;
      cl += 4;
    } else {
      float av[4] = {a0, a1, a2, a3};
#pragma unroll
      for (int k = 0; k < 4; ++k) {
        int g = wave_uniform(batch[i + k]);
        if (g != cur) {
          atomicAdd(&pooled[cur * 64 + lane], acc);
          if (lane == 0) atomicAdd(&cnt[cur], (float)cl);
          acc = 0.f; cl = 0; cur = g;
        }
        acc += av[k];
        cl += 1;
      }
    }
  }
  for (; i < end; ++i) {
    int g = wave_uniform(batch[i]);
    float a = x3[(size_t)i * 64 + lane];
    if (g != cur) {
      atomicAdd(&pooled[cur * 64 + lane], acc);
      if (lane == 0) atomicAdd(&cnt[cur], (float)cl);
      acc = 0.f; cl = 0; cur = g;
    }
    acc += a;
    cl += 1;
  }
  atomicAdd(&pooled[cur * 64 + lane], acc);
  if (lane == 0) atomicAdd(&cnt[cur], (float)cl);
}

// ---------- head: e = (pool/cnt)@Wlin + blin for both towers, L2 distance ----------
__global__ void k_final(const float* __restrict__ pooled1, const float* __restrict__ cnt1,
                        const float* __restrict__ pooled2, const float* __restrict__ cnt2,
                        const float* __restrict__ Wlin, const float* __restrict__ blin,
                        float* __restrict__ outp) {
  int g = blockIdx.x;
  int lane = threadIdx.x;  // 64 threads
  float c1 = fmaxf(cnt1[g], 1.f), c2 = fmaxf(cnt2[g], 1.f);
  float p1 = pooled1[g * 64 + lane] / c1;
  float p2 = pooled2[g * 64 + lane] / c2;
  float e1 = blin[lane], e2 = blin[lane];
  for (int j = 0; j < 64; ++j) {
    float w = Wlin[j * 64 + lane];
    e1 = fmaf(__shfl(p1, j), w, e1);
    e2 = fmaf(__shfl(p2, j), w, e2);
  }
  float d = e1 - e2 + PD_EPS;
  float sq = d * d;
  for (int o = 32; o > 0; o >>= 1) sq += __shfl_down(sq, o);
  if (lane == 0) outp[g] = sqrtf(sq);
}

extern "C" void kernel_launch(void* const* d_in, const int* in_sizes, int n_in,
                              void* d_out, int out_size, void* d_ws, size_t ws_size,
                              hipStream_t stream) {
  const float* x1 = (const float*)d_in[0];
  const int* ei1 = (const int*)d_in[1];
  const int* batch1 = (const int*)d_in[2];
  const float* x2 = (const float*)d_in[3];
  const int* ei2 = (const int*)d_in[4];
  const int* batch2 = (const int*)d_in[5];
  const float* W1 = (const float*)d_in[6];
  const float* b1 = (const float*)d_in[7];
  const float* W2 = (const float*)d_in[8];
  const float* b2 = (const float*)d_in[9];
  const float* W3 = (const float*)d_in[10];
  const float* b3 = (const float*)d_in[11];
  const float* Wlin = (const float*)d_in[12];
  const float* blin = (const float*)d_in[13];

  const int N = in_sizes[2];      // 100000
  const int E = in_sizes[1] / 2;  // 1600000

  // workspace carve (~60 MB)
  char* p = (char*)d_ws;
  auto alloc = [&](size_t bytes) {
    char* r = p;
    p += (bytes + 255) & ~(size_t)255;
    return r;
  };
  int* off = (int*)alloc((size_t)(N + 1) * 4);
  int* cntdeg = (int*)alloc((size_t)N * 4);
  int* cursor = (int*)alloc((size_t)N * 4);
  int* bsums = (int*)alloc(512 * 4);
  float* dinv = (float*)alloc((size_t)N * 4);
  int* csr = (int*)alloc((size_t)E * 4);
  float* bufA = (float*)alloc((size_t)N * 64 * 4);
  float* bufB = (float*)alloc((size_t)N * 64 * 4);
  float* pooled1 = (float*)alloc((size_t)NGRAPHS * 64 * 4);
  float* cnt1 = (float*)alloc((size_t)NGRAPHS * 4);
  float* pooled2 = (float*)alloc((size_t)NGRAPHS * 64 * 4);
  float* cnt2 = (float*)alloc((size_t)NGRAPHS * 4);

  const int nbN = (N + 255) / 256;
  const int nbE = (E + 255) / 256;

  for (int t = 0; t < 2; ++t) {
    const float* x = t ? x2 : x1;
    const int* src = t ? ei2 : ei1;
    const int* dst = src + E;
    const int* batch = t ? batch2 : batch1;
    float* pooled = t ? pooled2 : pooled1;
    float* cnt = t ? cnt2 : cnt1;

    hipMemsetAsync(cntdeg, 0, (size_t)N * 4, stream);
    hipMemsetAsync(pooled, 0, (size_t)NGRAPHS * 64 * 4, stream);
    hipMemsetAsync(cnt, 0, (size_t)NGRAPHS * 4, stream);

    k_count<<<nbE, 256, 0, stream>>>(dst, cntdeg, E);
    k_scan1<<<nbN, 256, 0, stream>>>(cntdeg, off, bsums, N);
    k_scan2<<<1, 512, 0, stream>>>(bsums, nbN);
    k_finalize<<<nbN, 256, 0, stream>>>(off, bsums, cursor, cntdeg, dinv, N, E);
    k_fill<<<nbE, 256, 0, stream>>>(src, dst, cursor, csr, E);

    // layer 1: x[N,128] -> bufB
    k_gemm<128><<<1024, 256, 0, stream>>>(x, W1, dinv, bufA, N);
    k_agg<<<2048, 256, 0, stream>>>(bufA, off, csr, dinv, b1, bufB, N, 1);
    // layer 2
    k_gemm<64><<<1024, 256, 0, stream>>>(bufB, W2, dinv, bufA, N);
    k_agg<<<2048, 256, 0, stream>>>(bufA, off, csr, dinv, b2, bufB, N, 1);
    // layer 3 (no relu)
    k_gemm<64><<<1024, 256, 0, stream>>>(bufB, W3, dinv, bufA, N);
    k_agg<<<2048, 256, 0, stream>>>(bufA, off, csr, dinv, b3, bufB, N, 0);

    const int poolWaves = (N + POOL_CHUNK - 1) / POOL_CHUNK;
    k_pool<<<(poolWaves + 3) / 4, 256, 0, stream>>>(bufB, batch, pooled, cnt, N);
  }
  k_final<<<NGRAPHS, 64, 0, stream>>>(pooled1, cnt1, pooled2, cnt2, Wlin, blin,
                                      (float*)d_out);
}

// Round 4
// 1090.434 us; speedup vs baseline: 2.9611x; 1.1494x over previous
//
#include <hip/hip_runtime.h>
#include <hip/hip_bf16.h>
#include <math.h>

#define NGRAPHS 256
#define PD_EPS 1e-6f
#define POOL_CHUNK 64
#define NCOLOR 8   // csr-build colors; blockIdx&7 ~ XCD id (round-robin dispatch)
#define KB 32      // blocks per color

typedef __hip_bfloat16 bf16;

static __device__ __forceinline__ int wave_uniform(int v) {
  return __builtin_amdgcn_readfirstlane(v);
}
static __device__ __forceinline__ float b2f(bf16 h) { return __bfloat162float(h); }
static __device__ __forceinline__ bf16 f2b(float f) { return __float2bfloat16(f); }

// ---------- pass1: per-(color,block) partial degree histogram in LDS ----------
// color = blockIdx&7 handles node range [color*rng, color*rng+rng); no device
// atomics (R3: 1.6M global atomics + 4B scatter ran at ~25 G ops/s = 130 us).
__global__ __launch_bounds__(256) void k_count_part(const int* __restrict__ dst,
                                                    int* __restrict__ partial, int E,
                                                    int n, int rng) {
  extern __shared__ int hist[];
  int color = blockIdx.x & (NCOLOR - 1);
  int sub = blockIdx.x >> 3;
  int base = color * rng;
  int hi = n - base; if (hi > rng) hi = rng;
  for (int i = threadIdx.x; i < rng; i += 256) hist[i] = 0;
  __syncthreads();
  int e = sub * 256 + threadIdx.x;
  for (; e + 3 * KB * 256 < E; e += 4 * KB * 256) {
    int d0 = dst[e] - base;
    int d1 = dst[e + KB * 256] - base;
    int d2 = dst[e + 2 * KB * 256] - base;
    int d3 = dst[e + 3 * KB * 256] - base;
    if ((unsigned)d0 < (unsigned)hi) atomicAdd(&hist[d0], 1);
    if ((unsigned)d1 < (unsigned)hi) atomicAdd(&hist[d1], 1);
    if ((unsigned)d2 < (unsigned)hi) atomicAdd(&hist[d2], 1);
    if ((unsigned)d3 < (unsigned)hi) atomicAdd(&hist[d3], 1);
  }
  for (; e < E; e += KB * 256) {
    int d = dst[e] - base;
    if ((unsigned)d < (unsigned)hi) atomicAdd(&hist[d], 1);
  }
  __syncthreads();
  int* outp = partial + (size_t)blockIdx.x * rng;
  for (int i = threadIdx.x; i < rng; i += 256) outp[i] = hist[i];
}

// ---------- pass2: reduce partials -> cnt + dinv; rewrite partials as
// exclusive prefix over sub-blocks (for the fill pass cursors) ----------
__global__ void k_reduce_part(int* __restrict__ partial, int* __restrict__ cnt,
                              float* __restrict__ dinv, int n, int rng) {
  int i = blockIdx.x * 256 + threadIdx.x;
  if (i >= n) return;
  int c = i / rng, li = i - c * rng;
  int acc = 0;
#pragma unroll
  for (int s = 0; s < KB; ++s) {
    size_t idx = (size_t)(s * NCOLOR + c) * rng + li;
    int t = partial[idx];
    partial[idx] = acc;
    acc += t;
  }
  cnt[i] = acc;
  dinv[i] = 1.0f / sqrtf((float)(acc + 1));  // self-loop => deg >= 1
}

// ---------- 3-phase exclusive scan (N=100k) ----------
__global__ void k_scan1(const int* __restrict__ cnt, int* __restrict__ off,
                        int* __restrict__ bsums, int n) {
  __shared__ int s[256];
  int tid = threadIdx.x;
  int gid = blockIdx.x * 256 + tid;
  int v = (gid < n) ? cnt[gid] : 0;
  s[tid] = v; __syncthreads();
  for (int o = 1; o < 256; o <<= 1) {
    int t = (tid >= o) ? s[tid - o] : 0;
    __syncthreads();
    s[tid] += t;
    __syncthreads();
  }
  if (gid < n) off[gid] = s[tid] - v;
  if (tid == 255) bsums[blockIdx.x] = s[255];
}

__global__ void k_scan2(int* __restrict__ bsums, int nb) {
  __shared__ int s[512];
  int tid = threadIdx.x;
  int v = (tid < nb) ? bsums[tid] : 0;
  s[tid] = v; __syncthreads();
  for (int o = 1; o < 512; o <<= 1) {
    int t = (tid >= o) ? s[tid - o] : 0;
    __syncthreads();
    s[tid] += t;
    __syncthreads();
  }
  if (tid < nb) bsums[tid] = s[tid] - v;
}

__global__ void k_off_final(int* __restrict__ off, const int* __restrict__ bsums,
                            int n, int E) {
  int gid = blockIdx.x * 256 + threadIdx.x;
  if (gid < n) off[gid] += bsums[blockIdx.x];
  if (gid == 0) off[n] = E;
}

// ---------- pass4: colored CSR fill. Same edge-slice assignment as pass1;
// LDS cursor = off[node] + inter-block prefix. Color's csr writes land in one
// contiguous ~E/8 window, hopefully XCD-local via blockIdx&7. ----------
__global__ __launch_bounds__(256) void k_fill_col(const int* __restrict__ src,
                                                  const int* __restrict__ dst,
                                                  const int* __restrict__ off,
                                                  const int* __restrict__ partial,
                                                  int* __restrict__ csr, int E, int n,
                                                  int rng) {
  extern __shared__ int cur[];
  int color = blockIdx.x & (NCOLOR - 1);
  int sub = blockIdx.x >> 3;
  int base = color * rng;
  int hi = n - base; if (hi > rng) hi = rng;
  const int* pp = partial + (size_t)blockIdx.x * rng;
  for (int i = threadIdx.x; i < hi; i += 256) cur[i] = off[base + i] + pp[i];
  __syncthreads();
  for (int e = sub * 256 + threadIdx.x; e < E; e += KB * 256) {
    int d = dst[e] - base;
    if ((unsigned)d < (unsigned)hi) {
      int s = src[e];
      int p = atomicAdd(&cur[d], 1);
      csr[p] = s;
    }
  }
}

// ---------- GEMM (f32 input rows) fused dinv scale, bf16 output ----------
// W column in VGPRs; K-loop FULLY unrolled (partial unroll -> dynamic w[]
// index -> scratch spill disaster, see R1). Node is readfirstlane'd so the
// x row goes down the scalar/broadcast path.
template <int K>
__global__ __launch_bounds__(256, 1) void k_gemm_f32(const float* __restrict__ in,
                                                     const float* __restrict__ Wg,
                                                     const float* __restrict__ dinv,
                                                     bf16* __restrict__ out, int n) {
  int lane = threadIdx.x & 63;
  int wid = (blockIdx.x * blockDim.x + threadIdx.x) >> 6;
  int nw = (gridDim.x * blockDim.x) >> 6;
  float w[K];
#pragma unroll
  for (int j = 0; j < K; ++j) w[j] = Wg[j * 64 + lane];
  for (int node = wid; node < n; node += nw) {
    int un = wave_uniform(node);
    const float* xr = in + (size_t)un * K;
    float acc = 0.f;
#pragma unroll
    for (int j4 = 0; j4 < K / 4; ++j4) {
      float4 xv = *(const float4*)(xr + 4 * j4);
      acc = fmaf(xv.x, w[4 * j4 + 0], acc);
      acc = fmaf(xv.y, w[4 * j4 + 1], acc);
      acc = fmaf(xv.z, w[4 * j4 + 2], acc);
      acc = fmaf(xv.w, w[4 * j4 + 3], acc);
    }
    out[(size_t)un * 64 + lane] = f2b(acc * dinv[un]);
  }
}

// ---------- GEMM (bf16 input rows, K=64) fused dinv scale, bf16 output ----------
__global__ __launch_bounds__(256, 1) void k_gemm_b16(const bf16* __restrict__ in,
                                                     const float* __restrict__ Wg,
                                                     const float* __restrict__ dinv,
                                                     bf16* __restrict__ out, int n) {
  int lane = threadIdx.x & 63;
  int wid = (blockIdx.x * blockDim.x + threadIdx.x) >> 6;
  int nw = (gridDim.x * blockDim.x) >> 6;
  float w[64];
#pragma unroll
  for (int j = 0; j < 64; ++j) w[j] = Wg[j * 64 + lane];
  for (int node = wid; node < n; node += nw) {
    int un = wave_uniform(node);
    const uint* xr = (const uint*)(in + (size_t)un * 64);
    float acc = 0.f;
#pragma unroll
    for (int q = 0; q < 8; ++q) {  // uint4 = 8 bf16 per iter
      uint4 u = *(const uint4*)(xr + 4 * q);
      acc = fmaf(__uint_as_float(u.x << 16),          w[8 * q + 0], acc);
      acc = fmaf(__uint_as_float(u.x & 0xffff0000u),  w[8 * q + 1], acc);
      acc = fmaf(__uint_as_float(u.y << 16),          w[8 * q + 2], acc);
      acc = fmaf(__uint_as_float(u.y & 0xffff0000u),  w[8 * q + 3], acc);
      acc = fmaf(__uint_as_float(u.z << 16),          w[8 * q + 4], acc);
      acc = fmaf(__uint_as_float(u.z & 0xffff0000u),  w[8 * q + 5], acc);
      acc = fmaf(__uint_as_float(u.w << 16),          w[8 * q + 6], acc);
      acc = fmaf(__uint_as_float(u.w & 0xffff0000u),  w[8 * q + 7], acc);
    }
    out[(size_t)un * 64 + lane] = f2b(acc * dinv[un]);
  }
}

// ---------- aggregate: out[d] = act(dinv[d]*(sum_{s in N(d)} h'[s] + h'[d]) + b)
// hp is bf16 (halves the LLC gather volume: 410 -> 205 MB/layer). f32 accum.
template <int OUTF32>
__global__ __launch_bounds__(256) void k_agg(const bf16* __restrict__ hp,
                                             const int* __restrict__ off,
                                             const int* __restrict__ csr,
                                             const float* __restrict__ dinv,
                                             const float* __restrict__ bias,
                                             void* __restrict__ outv, int n,
                                             int do_relu) {
  int lane = threadIdx.x & 63;
  int wid = (blockIdx.x * blockDim.x + threadIdx.x) >> 6;
  int nw = (gridDim.x * blockDim.x) >> 6;
  float b = bias[lane];
  for (int node = wid; node < n; node += nw) {
    int un = wave_uniform(node);
    int beg = off[un], end = off[un + 1];
    float acc = b2f(hp[(size_t)un * 64 + lane]);  // self-loop
    int e = beg;
    for (; e + 8 <= end; e += 8) {
      int s0 = csr[e + 0], s1 = csr[e + 1], s2 = csr[e + 2], s3 = csr[e + 3];
      int s4 = csr[e + 4], s5 = csr[e + 5], s6 = csr[e + 6], s7 = csr[e + 7];
      float a0 = b2f(hp[(size_t)s0 * 64 + lane]);
      float a1 = b2f(hp[(size_t)s1 * 64 + lane]);
      float a2 = b2f(hp[(size_t)s2 * 64 + lane]);
      float a3 = b2f(hp[(size_t)s3 * 64 + lane]);
      float a4 = b2f(hp[(size_t)s4 * 64 + lane]);
      float a5 = b2f(hp[(size_t)s5 * 64 + lane]);
      float a6 = b2f(hp[(size_t)s6 * 64 + lane]);
      float a7 = b2f(hp[(size_t)s7 * 64 + lane]);
      acc += ((a0 + a1) + (a2 + a3)) + ((a4 + a5) + (a6 + a7));
    }
    for (; e < end; ++e) acc += b2f(hp[(size_t)csr[e] * 64 + lane]);
    float v = fmaf(acc, dinv[un], b);
    if (do_relu) v = fmaxf(v, 0.f);
    if (OUTF32)
      ((float*)outv)[(size_t)un * 64 + lane] = v;
    else
      ((bf16*)outv)[(size_t)un * 64 + lane] = f2b(v);
  }
}

// ---------- mean-pool: segment-reduce over sorted batch (R2 fix) ----------
__global__ __launch_bounds__(256) void k_pool(const float* __restrict__ x3,
                                              const int* __restrict__ batch,
                                              float* __restrict__ pooled,
                                              float* __restrict__ cnt, int n) {
  int lane = threadIdx.x & 63;
  int wid = (blockIdx.x * blockDim.x + threadIdx.x) >> 6;
  int beg = wid * POOL_CHUNK;
  if (beg >= n) return;
  int end = beg + POOL_CHUNK;
  if (end > n) end = n;

  int cur = wave_uniform(batch[beg]);
  float acc = 0.f;
  int cl = 0;
  int i = beg;
  for (; i + 4 <= end; i += 4) {
    int g0 = wave_uniform(batch[i + 0]);
    int g3 = wave_uniform(batch[i + 3]);
    float a0 = x3[(size_t)(i + 0) * 64 + lane];
    float a1 = x3[(size_t)(i + 1) * 64 + lane];
    float a2 = x3[(size_t)(i + 2) * 64 + lane];
    float a3 = x3[(size_t)(i + 3) * 64 + lane];
    if (g0 == cur && g3 == cur) {
      acc += a0 + a1 + a2 + a3;
      cl += 4;
    } else {
      float av[4] = {a0, a1, a2, a3};
#pragma unroll
      for (int k = 0; k < 4; ++k) {
        int g = wave_uniform(batch[i + k]);
        if (g != cur) {
          atomicAdd(&pooled[cur * 64 + lane], acc);
          if (lane == 0) atomicAdd(&cnt[cur], (float)cl);
          acc = 0.f; cl = 0; cur = g;
        }
        acc += av[k];
        cl += 1;
      }
    }
  }
  for (; i < end; ++i) {
    int g = wave_uniform(batch[i]);
    float a = x3[(size_t)i * 64 + lane];
    if (g != cur) {
      atomicAdd(&pooled[cur * 64 + lane], acc);
      if (lane == 0) atomicAdd(&cnt[cur], (float)cl);
      acc = 0.f; cl = 0; cur = g;
    }
    acc += a;
    cl += 1;
  }
  atomicAdd(&pooled[cur * 64 + lane], acc);
  if (lane == 0) atomicAdd(&cnt[cur], (float)cl);
}

// ---------- head: both 64x64 GEMMs + L2 distance ----------
__global__ void k_final(const float* __restrict__ pooled1, const float* __restrict__ cnt1,
                        const float* __restrict__ pooled2, const float* __restrict__ cnt2,
                        const float* __restrict__ Wlin, const float* __restrict__ blin,
                        float* __restrict__ outp) {
  int g = blockIdx.x;
  int lane = threadIdx.x;  // 64 threads
  float c1 = fmaxf(cnt1[g], 1.f), c2 = fmaxf(cnt2[g], 1.f);
  float p1 = pooled1[g * 64 + lane] / c1;
  float p2 = pooled2[g * 64 + lane] / c2;
  float e1 = blin[lane], e2 = blin[lane];
  for (int j = 0; j < 64; ++j) {
    float w = Wlin[j * 64 + lane];
    e1 = fmaf(__shfl(p1, j), w, e1);
    e2 = fmaf(__shfl(p2, j), w, e2);
  }
  float d = e1 - e2 + PD_EPS;
  float sq = d * d;
  for (int o = 32; o > 0; o >>= 1) sq += __shfl_down(sq, o);
  if (lane == 0) outp[g] = sqrtf(sq);
}

extern "C" void kernel_launch(void* const* d_in, const int* in_sizes, int n_in,
                              void* d_out, int out_size, void* d_ws, size_t ws_size,
                              hipStream_t stream) {
  const float* x1 = (const float*)d_in[0];
  const int* ei1 = (const int*)d_in[1];
  const int* batch1 = (const int*)d_in[2];
  const float* x2 = (const float*)d_in[3];
  const int* ei2 = (const int*)d_in[4];
  const int* batch2 = (const int*)d_in[5];
  const float* W1 = (const float*)d_in[6];
  const float* b1 = (const float*)d_in[7];
  const float* W2 = (const float*)d_in[8];
  const float* b2 = (const float*)d_in[9];
  const float* W3 = (const float*)d_in[10];
  const float* b3 = (const float*)d_in[11];
  const float* Wlin = (const float*)d_in[12];
  const float* blin = (const float*)d_in[13];

  const int N = in_sizes[2];      // 100000
  const int E = in_sizes[1] / 2;  // 1600000
  const int rng = (N + NCOLOR - 1) / NCOLOR;  // nodes per color (12500)

  // workspace carve (~59 MB); partial (12.8 MB) aliases bufF (25.6 MB):
  // partial dead after k_fill_col, bufF born at agg3 of the same tower.
  char* p = (char*)d_ws;
  auto alloc = [&](size_t bytes) {
    char* r = p;
    p += (bytes + 255) & ~(size_t)255;
    return r;
  };
  int* off = (int*)alloc((size_t)(N + 1) * 4);
  int* cntn = (int*)alloc((size_t)N * 4);
  int* bsums = (int*)alloc(512 * 4);
  float* dinv = (float*)alloc((size_t)N * 4);
  int* csr = (int*)alloc((size_t)E * 4);
  char* unionbuf = alloc((size_t)N * 64 * 4);  // max(partial 12.8MB, bufF 25.6MB)
  int* partial = (int*)unionbuf;
  float* bufF = (float*)unionbuf;
  bf16* hpA = (bf16*)alloc((size_t)N * 64 * 2);
  bf16* hpB = (bf16*)alloc((size_t)N * 64 * 2);
  float* pooled1 = (float*)alloc((size_t)NGRAPHS * 64 * 4);
  float* cnt1 = (float*)alloc((size_t)NGRAPHS * 4);
  float* pooled2 = (float*)alloc((size_t)NGRAPHS * 64 * 4);
  float* cnt2 = (float*)alloc((size_t)NGRAPHS * 4);

  const int nbN = (N + 255) / 256;
  const size_t ldsB = (size_t)rng * 4;  // 50 KB dynamic LDS

  for (int t = 0; t < 2; ++t) {
    const float* x = t ? x2 : x1;
    const int* src = t ? ei2 : ei1;
    const int* dst = src + E;
    const int* batch = t ? batch2 : batch1;
    float* pooled = t ? pooled2 : pooled1;
    float* cnt = t ? cnt2 : cnt1;

    hipMemsetAsync(pooled, 0, (size_t)NGRAPHS * 64 * 4, stream);
    hipMemsetAsync(cnt, 0, (size_t)NGRAPHS * 4, stream);

    // CSR build: colored, no device atomics
    k_count_part<<<NCOLOR * KB, 256, ldsB, stream>>>(dst, partial, E, N, rng);
    k_reduce_part<<<nbN, 256, 0, stream>>>(partial, cntn, dinv, N, rng);
    k_scan1<<<nbN, 256, 0, stream>>>(cntn, off, bsums, N);
    k_scan2<<<1, 512, 0, stream>>>(bsums, nbN);
    k_off_final<<<nbN, 256, 0, stream>>>(off, bsums, N, E);
    k_fill_col<<<NCOLOR * KB, 256, ldsB, stream>>>(src, dst, off, partial, csr, E, N,
                                                   rng);

    // layer 1
    k_gemm_f32<128><<<1024, 256, 0, stream>>>(x, W1, dinv, hpA, N);
    k_agg<0><<<2048, 256, 0, stream>>>(hpA, off, csr, dinv, b1, hpB, N, 1);
    // layer 2
    k_gemm_b16<<<1024, 256, 0, stream>>>(hpB, W2, dinv, hpA, N);
    k_agg<0><<<2048, 256, 0, stream>>>(hpA, off, csr, dinv, b2, hpB, N, 1);
    // layer 3 (no relu), f32 out for pooling
    k_gemm_b16<<<1024, 256, 0, stream>>>(hpB, W3, dinv, hpA, N);
    k_agg<1><<<2048, 256, 0, stream>>>(hpA, off, csr, dinv, b3, bufF, N, 0);

    const int poolWaves = (N + POOL_CHUNK - 1) / POOL_CHUNK;
    k_pool<<<(poolWaves + 3) / 4, 256, 0, stream>>>(bufF, batch, pooled, cnt, N);
  }
  k_final<<<NGRAPHS, 64, 0, stream>>>(pooled1, cnt1, pooled2, cnt2, Wlin, blin,
                                      (float*)d_out);
}

// Round 5
// 938.000 us; speedup vs baseline: 3.4423x; 1.1625x over previous
//
#include <hip/hip_runtime.h>
#include <hip/hip_bf16.h>
#include <math.h>

#define NGRAPHS 256
#define PD_EPS 1e-6f
#define POOL_CHUNK 64
#define NCOLOR 8   // csr-build colors; blockIdx&7 ~ XCD id (round-robin dispatch)
#define KB 96      // blocks per color; grid=768 -> 3 blocks/CU (LDS limit), 12 waves/CU
                   // (R4: KB=32 -> 1 block/CU -> 11% occupancy -> 133 us latency-bound)

typedef __hip_bfloat16 bf16;
typedef unsigned short ushort_t;

static __device__ __forceinline__ int wave_uniform(int v) {
  return __builtin_amdgcn_readfirstlane(v);
}
static __device__ __forceinline__ float b2f(bf16 h) { return __bfloat162float(h); }
static __device__ __forceinline__ bf16 f2b(float f) { return __float2bfloat16(f); }

// ---------- pass1: per-(color,block) partial degree histogram in LDS ----------
// color = blockIdx&7 handles node range [color*rng, color*rng+rng); no device
// atomics (R3: 1.6M global atomics + 4B scatter ran at ~25 G ops/s = 130 us).
// Per-(block,node) counts are tiny (<=~15) -> partial stored as ushort.
__global__ __launch_bounds__(256) void k_count_part(const int* __restrict__ dst,
                                                    ushort_t* __restrict__ partial,
                                                    int E, int n, int rng) {
  extern __shared__ int hist[];
  int color = blockIdx.x & (NCOLOR - 1);
  int sub = blockIdx.x >> 3;
  int base = color * rng;
  int hi = n - base; if (hi > rng) hi = rng;
  for (int i = threadIdx.x; i < rng; i += 256) hist[i] = 0;
  __syncthreads();
  int e = sub * 256 + threadIdx.x;
  for (; e + 3 * KB * 256 < E; e += 4 * KB * 256) {
    int d0 = dst[e] - base;
    int d1 = dst[e + KB * 256] - base;
    int d2 = dst[e + 2 * KB * 256] - base;
    int d3 = dst[e + 3 * KB * 256] - base;
    if ((unsigned)d0 < (unsigned)hi) atomicAdd(&hist[d0], 1);
    if ((unsigned)d1 < (unsigned)hi) atomicAdd(&hist[d1], 1);
    if ((unsigned)d2 < (unsigned)hi) atomicAdd(&hist[d2], 1);
    if ((unsigned)d3 < (unsigned)hi) atomicAdd(&hist[d3], 1);
  }
  for (; e < E; e += KB * 256) {
    int d = dst[e] - base;
    if ((unsigned)d < (unsigned)hi) atomicAdd(&hist[d], 1);
  }
  __syncthreads();
  ushort_t* outp = partial + (size_t)blockIdx.x * rng;
  for (int i = threadIdx.x; i < rng; i += 256) outp[i] = (ushort_t)hist[i];
}

// ---------- pass2: reduce partials -> cnt + dinv; rewrite partials as
// exclusive prefix over sub-blocks (for the fill pass cursors) ----------
__global__ void k_reduce_part(ushort_t* __restrict__ partial, int* __restrict__ cnt,
                              float* __restrict__ dinv, int n, int rng) {
  int i = blockIdx.x * 256 + threadIdx.x;
  if (i >= n) return;
  int c = i / rng, li = i - c * rng;
  int acc = 0;
  for (int s = 0; s < KB; ++s) {
    size_t idx = (size_t)(s * NCOLOR + c) * rng + li;
    int t = partial[idx];
    partial[idx] = (ushort_t)acc;
    acc += t;
  }
  cnt[i] = acc;
  dinv[i] = 1.0f / sqrtf((float)(acc + 1));  // self-loop => deg >= 1
}

// ---------- 3-phase exclusive scan (N=100k) ----------
__global__ void k_scan1(const int* __restrict__ cnt, int* __restrict__ off,
                        int* __restrict__ bsums, int n) {
  __shared__ int s[256];
  int tid = threadIdx.x;
  int gid = blockIdx.x * 256 + tid;
  int v = (gid < n) ? cnt[gid] : 0;
  s[tid] = v; __syncthreads();
  for (int o = 1; o < 256; o <<= 1) {
    int t = (tid >= o) ? s[tid - o] : 0;
    __syncthreads();
    s[tid] += t;
    __syncthreads();
  }
  if (gid < n) off[gid] = s[tid] - v;
  if (tid == 255) bsums[blockIdx.x] = s[255];
}

__global__ void k_scan2(int* __restrict__ bsums, int nb) {
  __shared__ int s[512];
  int tid = threadIdx.x;
  int v = (tid < nb) ? bsums[tid] : 0;
  s[tid] = v; __syncthreads();
  for (int o = 1; o < 512; o <<= 1) {
    int t = (tid >= o) ? s[tid - o] : 0;
    __syncthreads();
    s[tid] += t;
    __syncthreads();
  }
  if (tid < nb) bsums[tid] = s[tid] - v;
}

__global__ void k_off_final(int* __restrict__ off, const int* __restrict__ bsums,
                            int n, int E) {
  int gid = blockIdx.x * 256 + threadIdx.x;
  if (gid < n) off[gid] += bsums[blockIdx.x];
  if (gid == 0) off[n] = E;
}

// ---------- pass4: colored CSR fill. Same edge-slice assignment as pass1;
// LDS cursor = off[node] + inter-block prefix. Color's csr writes land in one
// contiguous ~E/8 window (R4: WRITE_SIZE 105 -> 11.5 MB). ----------
__global__ __launch_bounds__(256) void k_fill_col(const int* __restrict__ src,
                                                  const int* __restrict__ dst,
                                                  const int* __restrict__ off,
                                                  const ushort_t* __restrict__ partial,
                                                  int* __restrict__ csr, int E, int n,
                                                  int rng) {
  extern __shared__ int cur[];
  int color = blockIdx.x & (NCOLOR - 1);
  int sub = blockIdx.x >> 3;
  int base = color * rng;
  int hi = n - base; if (hi > rng) hi = rng;
  const ushort_t* pp = partial + (size_t)blockIdx.x * rng;
  for (int i = threadIdx.x; i < hi; i += 256) cur[i] = off[base + i] + (int)pp[i];
  __syncthreads();
  for (int e = sub * 256 + threadIdx.x; e < E; e += KB * 256) {
    int d = dst[e] - base;
    if ((unsigned)d < (unsigned)hi) {
      int s = src[e];
      int p = atomicAdd(&cur[d], 1);
      csr[p] = s;
    }
  }
}

// ---------- GEMM (f32 input rows) fused dinv scale, bf16 output ----------
// W column in VGPRs; K-loop FULLY unrolled (partial unroll -> dynamic w[]
// index -> scratch spill disaster, see R1). Node is readfirstlane'd so the
// x row goes down the scalar/broadcast path.
template <int K>
__global__ __launch_bounds__(256, 1) void k_gemm_f32(const float* __restrict__ in,
                                                     const float* __restrict__ Wg,
                                                     const float* __restrict__ dinv,
                                                     bf16* __restrict__ out, int n) {
  int lane = threadIdx.x & 63;
  int wid = (blockIdx.x * blockDim.x + threadIdx.x) >> 6;
  int nw = (gridDim.x * blockDim.x) >> 6;
  float w[K];
#pragma unroll
  for (int j = 0; j < K; ++j) w[j] = Wg[j * 64 + lane];
  for (int node = wid; node < n; node += nw) {
    int un = wave_uniform(node);
    const float* xr = in + (size_t)un * K;
    float acc = 0.f;
#pragma unroll
    for (int j4 = 0; j4 < K / 4; ++j4) {
      float4 xv = *(const float4*)(xr + 4 * j4);
      acc = fmaf(xv.x, w[4 * j4 + 0], acc);
      acc = fmaf(xv.y, w[4 * j4 + 1], acc);
      acc = fmaf(xv.z, w[4 * j4 + 2], acc);
      acc = fmaf(xv.w, w[4 * j4 + 3], acc);
    }
    out[(size_t)un * 64 + lane] = f2b(acc * dinv[un]);
  }
}

// ---------- GEMM (bf16 input rows, K=64) fused dinv scale, bf16 output ----------
__global__ __launch_bounds__(256, 1) void k_gemm_b16(const bf16* __restrict__ in,
                                                     const float* __restrict__ Wg,
                                                     const float* __restrict__ dinv,
                                                     bf16* __restrict__ out, int n) {
  int lane = threadIdx.x & 63;
  int wid = (blockIdx.x * blockDim.x + threadIdx.x) >> 6;
  int nw = (gridDim.x * blockDim.x) >> 6;
  float w[64];
#pragma unroll
  for (int j = 0; j < 64; ++j) w[j] = Wg[j * 64 + lane];
  for (int node = wid; node < n; node += nw) {
    int un = wave_uniform(node);
    const uint* xr = (const uint*)(in + (size_t)un * 64);
    float acc = 0.f;
#pragma unroll
    for (int q = 0; q < 8; ++q) {  // uint4 = 8 bf16 per iter
      uint4 u = *(const uint4*)(xr + 4 * q);
      acc = fmaf(__uint_as_float(u.x << 16),          w[8 * q + 0], acc);
      acc = fmaf(__uint_as_float(u.x & 0xffff0000u),  w[8 * q + 1], acc);
      acc = fmaf(__uint_as_float(u.y << 16),          w[8 * q + 2], acc);
      acc = fmaf(__uint_as_float(u.y & 0xffff0000u),  w[8 * q + 3], acc);
      acc = fmaf(__uint_as_float(u.z << 16),          w[8 * q + 4], acc);
      acc = fmaf(__uint_as_float(u.z & 0xffff0000u),  w[8 * q + 5], acc);
      acc = fmaf(__uint_as_float(u.w << 16),          w[8 * q + 6], acc);
      acc = fmaf(__uint_as_float(u.w & 0xffff0000u),  w[8 * q + 7], acc);
    }
    out[(size_t)un * 64 + lane] = f2b(acc * dinv[un]);
  }
}

// ---------- aggregate: out[d] = act(dinv[d]*(sum_{s in N(d)} h'[s] + h'[d]) + b)
// hp is bf16 (halves the LLC gather volume: 410 -> 205 MB/layer). f32 accum.
template <int OUTF32>
__global__ __launch_bounds__(256) void k_agg(const bf16* __restrict__ hp,
                                             const int* __restrict__ off,
                                             const int* __restrict__ csr,
                                             const float* __restrict__ dinv,
                                             const float* __restrict__ bias,
                                             void* __restrict__ outv, int n,
                                             int do_relu) {
  int lane = threadIdx.x & 63;
  int wid = (blockIdx.x * blockDim.x + threadIdx.x) >> 6;
  int nw = (gridDim.x * blockDim.x) >> 6;
  float b = bias[lane];
  for (int node = wid; node < n; node += nw) {
    int un = wave_uniform(node);
    int beg = off[un], end = off[un + 1];
    float acc = b2f(hp[(size_t)un * 64 + lane]);  // self-loop
    int e = beg;
    for (; e + 8 <= end; e += 8) {
      int s0 = csr[e + 0], s1 = csr[e + 1], s2 = csr[e + 2], s3 = csr[e + 3];
      int s4 = csr[e + 4], s5 = csr[e + 5], s6 = csr[e + 6], s7 = csr[e + 7];
      float a0 = b2f(hp[(size_t)s0 * 64 + lane]);
      float a1 = b2f(hp[(size_t)s1 * 64 + lane]);
      float a2 = b2f(hp[(size_t)s2 * 64 + lane]);
      float a3 = b2f(hp[(size_t)s3 * 64 + lane]);
      float a4 = b2f(hp[(size_t)s4 * 64 + lane]);
      float a5 = b2f(hp[(size_t)s5 * 64 + lane]);
      float a6 = b2f(hp[(size_t)s6 * 64 + lane]);
      float a7 = b2f(hp[(size_t)s7 * 64 + lane]);
      acc += ((a0 + a1) + (a2 + a3)) + ((a4 + a5) + (a6 + a7));
    }
    for (; e < end; ++e) acc += b2f(hp[(size_t)csr[e] * 64 + lane]);
    float v = fmaf(acc, dinv[un], b);
    if (do_relu) v = fmaxf(v, 0.f);
    if (OUTF32)
      ((float*)outv)[(size_t)un * 64 + lane] = v;
    else
      ((bf16*)outv)[(size_t)un * 64 + lane] = f2b(v);
  }
}

// ---------- mean-pool: segment-reduce over sorted batch (R2 fix) ----------
__global__ __launch_bounds__(256) void k_pool(const float* __restrict__ x3,
                                              const int* __restrict__ batch,
                                              float* __restrict__ pooled,
                                              float* __restrict__ cnt, int n) {
  int lane = threadIdx.x & 63;
  int wid = (blockIdx.x * blockDim.x + threadIdx.x) >> 6;
  int beg = wid * POOL_CHUNK;
  if (beg >= n) return;
  int end = beg + POOL_CHUNK;
  if (end > n) end = n;

  int cur = wave_uniform(batch[beg]);
  float acc = 0.f;
  int cl = 0;
  int i = beg;
  for (; i + 4 <= end; i += 4) {
    int g0 = wave_uniform(batch[i + 0]);
    int g3 = wave_uniform(batch[i + 3]);
    float a0 = x3[(size_t)(i + 0) * 64 + lane];
    float a1 = x3[(size_t)(i + 1) * 64 + lane];
    float a2 = x3[(size_t)(i + 2) * 64 + lane];
    float a3 = x3[(size_t)(i + 3) * 64 + lane];
    if (g0 == cur && g3 == cur) {
      acc += a0 + a1 + a2 + a3;
      cl += 4;
    } else {
      float av[4] = {a0, a1, a2, a3};
#pragma unroll
      for (int k = 0; k < 4; ++k) {
        int g = wave_uniform(batch[i + k]);
        if (g != cur) {
          atomicAdd(&pooled[cur * 64 + lane], acc);
          if (lane == 0) atomicAdd(&cnt[cur], (float)cl);
          acc = 0.f; cl = 0; cur = g;
        }
        acc += av[k];
        cl += 1;
      }
    }
  }
  for (; i < end; ++i) {
    int g = wave_uniform(batch[i]);
    float a = x3[(size_t)i * 64 + lane];
    if (g != cur) {
      atomicAdd(&pooled[cur * 64 + lane], acc);
      if (lane == 0) atomicAdd(&cnt[cur], (float)cl);
      acc = 0.f; cl = 0; cur = g;
    }
    acc += a;
    cl += 1;
  }
  atomicAdd(&pooled[cur * 64 + lane], acc);
  if (lane == 0) atomicAdd(&cnt[cur], (float)cl);
}

// ---------- head: both 64x64 GEMMs + L2 distance ----------
__global__ void k_final(const float* __restrict__ pooled1, const float* __restrict__ cnt1,
                        const float* __restrict__ pooled2, const float* __restrict__ cnt2,
                        const float* __restrict__ Wlin, const float* __restrict__ blin,
                        float* __restrict__ outp) {
  int g = blockIdx.x;
  int lane = threadIdx.x;  // 64 threads
  float c1 = fmaxf(cnt1[g], 1.f), c2 = fmaxf(cnt2[g], 1.f);
  float p1 = pooled1[g * 64 + lane] / c1;
  float p2 = pooled2[g * 64 + lane] / c2;
  float e1 = blin[lane], e2 = blin[lane];
  for (int j = 0; j < 64; ++j) {
    float w = Wlin[j * 64 + lane];
    e1 = fmaf(__shfl(p1, j), w, e1);
    e2 = fmaf(__shfl(p2, j), w, e2);
  }
  float d = e1 - e2 + PD_EPS;
  float sq = d * d;
  for (int o = 32; o > 0; o >>= 1) sq += __shfl_down(sq, o);
  if (lane == 0) outp[g] = sqrtf(sq);
}

extern "C" void kernel_launch(void* const* d_in, const int* in_sizes, int n_in,
                              void* d_out, int out_size, void* d_ws, size_t ws_size,
                              hipStream_t stream) {
  const float* x1 = (const float*)d_in[0];
  const int* ei1 = (const int*)d_in[1];
  const int* batch1 = (const int*)d_in[2];
  const float* x2 = (const float*)d_in[3];
  const int* ei2 = (const int*)d_in[4];
  const int* batch2 = (const int*)d_in[5];
  const float* W1 = (const float*)d_in[6];
  const float* b1 = (const float*)d_in[7];
  const float* W2 = (const float*)d_in[8];
  const float* b2 = (const float*)d_in[9];
  const float* W3 = (const float*)d_in[10];
  const float* b3 = (const float*)d_in[11];
  const float* Wlin = (const float*)d_in[12];
  const float* blin = (const float*)d_in[13];

  const int N = in_sizes[2];      // 100000
  const int E = in_sizes[1] / 2;  // 1600000
  const int rng = (N + NCOLOR - 1) / NCOLOR;  // nodes per color (12500)

  // workspace carve (~59 MB); partial (768*12500 ushort = 19.2 MB) aliases
  // bufF (25.6 MB): partial dead after k_fill_col, bufF born at agg3.
  char* p = (char*)d_ws;
  auto alloc = [&](size_t bytes) {
    char* r = p;
    p += (bytes + 255) & ~(size_t)255;
    return r;
  };
  int* off = (int*)alloc((size_t)(N + 1) * 4);
  int* cntn = (int*)alloc((size_t)N * 4);
  int* bsums = (int*)alloc(512 * 4);
  float* dinv = (float*)alloc((size_t)N * 4);
  int* csr = (int*)alloc((size_t)E * 4);
  char* unionbuf = alloc((size_t)N * 64 * 4);  // max(partial 19.2MB, bufF 25.6MB)
  ushort_t* partial = (ushort_t*)unionbuf;
  float* bufF = (float*)unionbuf;
  bf16* hpA = (bf16*)alloc((size_t)N * 64 * 2);
  bf16* hpB = (bf16*)alloc((size_t)N * 64 * 2);
  float* pooled1 = (float*)alloc((size_t)NGRAPHS * 64 * 4);
  float* cnt1 = (float*)alloc((size_t)NGRAPHS * 4);
  float* pooled2 = (float*)alloc((size_t)NGRAPHS * 64 * 4);
  float* cnt2 = (float*)alloc((size_t)NGRAPHS * 4);

  const int nbN = (N + 255) / 256;
  const size_t ldsB = (size_t)rng * 4;  // 50 KB dynamic LDS -> 3 blocks/CU

  for (int t = 0; t < 2; ++t) {
    const float* x = t ? x2 : x1;
    const int* src = t ? ei2 : ei1;
    const int* dst = src + E;
    const int* batch = t ? batch2 : batch1;
    float* pooled = t ? pooled2 : pooled1;
    float* cnt = t ? cnt2 : cnt1;

    hipMemsetAsync(pooled, 0, (size_t)NGRAPHS * 64 * 4, stream);
    hipMemsetAsync(cnt, 0, (size_t)NGRAPHS * 4, stream);

    // CSR build: colored, no device atomics; grid 768 = 3 blocks/CU
    k_count_part<<<NCOLOR * KB, 256, ldsB, stream>>>(dst, partial, E, N, rng);
    k_reduce_part<<<nbN, 256, 0, stream>>>(partial, cntn, dinv, N, rng);
    k_scan1<<<nbN, 256, 0, stream>>>(cntn, off, bsums, N);
    k_scan2<<<1, 512, 0, stream>>>(bsums, nbN);
    k_off_final<<<nbN, 256, 0, stream>>>(off, bsums, N, E);
    k_fill_col<<<NCOLOR * KB, 256, ldsB, stream>>>(src, dst, off, partial, csr, E, N,
                                                   rng);

    // layer 1
    k_gemm_f32<128><<<1024, 256, 0, stream>>>(x, W1, dinv, hpA, N);
    k_agg<0><<<2048, 256, 0, stream>>>(hpA, off, csr, dinv, b1, hpB, N, 1);
    // layer 2
    k_gemm_b16<<<1024, 256, 0, stream>>>(hpB, W2, dinv, hpA, N);
    k_agg<0><<<2048, 256, 0, stream>>>(hpA, off, csr, dinv, b2, hpB, N, 1);
    // layer 3 (no relu), f32 out for pooling
    k_gemm_b16<<<1024, 256, 0, stream>>>(hpB, W3, dinv, hpA, N);
    k_agg<1><<<2048, 256, 0, stream>>>(hpA, off, csr, dinv, b3, bufF, N, 0);

    const int poolWaves = (N + POOL_CHUNK - 1) / POOL_CHUNK;
    k_pool<<<(poolWaves + 3) / 4, 256, 0, stream>>>(bufF, batch, pooled, cnt, N);
  }
  k_final<<<NGRAPHS, 64, 0, stream>>>(pooled1, cnt1, pooled2, cnt2, Wlin, blin,
                                      (float*)d_out);
}

// Round 6
// 710.798 us; speedup vs baseline: 4.5426x; 1.3196x over previous
//
#include <hip/hip_runtime.h>
#include <hip/hip_bf16.h>
#include <math.h>

#define NGRAPHS 256
#define PD_EPS 1e-6f
#define POOL_CHUNK 64
#define NCOLOR 8   // csr-build colors; blockIdx&7 ~ XCD id (round-robin dispatch)
#define KB 96      // blocks per color; grid=768 -> 3 blocks/CU (LDS limit), 12 waves/CU

typedef __hip_bfloat16 bf16;
typedef unsigned short ushort_t;
typedef short bf8_t __attribute__((ext_vector_type(8)));   // 8 bf16 = 4 VGPRs
typedef float f4_t __attribute__((ext_vector_type(4)));    // MFMA accumulator

static __device__ __forceinline__ int wave_uniform(int v) {
  return __builtin_amdgcn_readfirstlane(v);
}
static __device__ __forceinline__ float b2f(bf16 h) { return __bfloat162float(h); }
static __device__ __forceinline__ bf16 f2b(float f) { return __float2bfloat16(f); }
static __device__ __forceinline__ short f2bbits(float f) {
  bf16 h = __float2bfloat16(f);
  return *reinterpret_cast<short*>(&h);
}

// ---------- pass1: per-(color,block) partial degree histogram in LDS ----------
__global__ __launch_bounds__(256) void k_count_part(const int* __restrict__ dst,
                                                    ushort_t* __restrict__ partial,
                                                    int E, int n, int rng) {
  extern __shared__ int hist[];
  int color = blockIdx.x & (NCOLOR - 1);
  int sub = blockIdx.x >> 3;
  int base = color * rng;
  int hi = n - base; if (hi > rng) hi = rng;
  for (int i = threadIdx.x; i < rng; i += 256) hist[i] = 0;
  __syncthreads();
  int e = sub * 256 + threadIdx.x;
  for (; e + 3 * KB * 256 < E; e += 4 * KB * 256) {
    int d0 = dst[e] - base;
    int d1 = dst[e + KB * 256] - base;
    int d2 = dst[e + 2 * KB * 256] - base;
    int d3 = dst[e + 3 * KB * 256] - base;
    if ((unsigned)d0 < (unsigned)hi) atomicAdd(&hist[d0], 1);
    if ((unsigned)d1 < (unsigned)hi) atomicAdd(&hist[d1], 1);
    if ((unsigned)d2 < (unsigned)hi) atomicAdd(&hist[d2], 1);
    if ((unsigned)d3 < (unsigned)hi) atomicAdd(&hist[d3], 1);
  }
  for (; e < E; e += KB * 256) {
    int d = dst[e] - base;
    if ((unsigned)d < (unsigned)hi) atomicAdd(&hist[d], 1);
  }
  __syncthreads();
  ushort_t* outp = partial + (size_t)blockIdx.x * rng;
  for (int i = threadIdx.x; i < rng; i += 256) outp[i] = (ushort_t)hist[i];
}

// ---------- pass2: reduce partials -> cnt + dinv; partials -> exclusive prefix ----------
__global__ void k_reduce_part(ushort_t* __restrict__ partial, int* __restrict__ cnt,
                              float* __restrict__ dinv, int n, int rng) {
  int i = blockIdx.x * 256 + threadIdx.x;
  if (i >= n) return;
  int c = i / rng, li = i - c * rng;
  int acc = 0;
  for (int s = 0; s < KB; ++s) {
    size_t idx = (size_t)(s * NCOLOR + c) * rng + li;
    int t = partial[idx];
    partial[idx] = (ushort_t)acc;
    acc += t;
  }
  cnt[i] = acc;
  dinv[i] = 1.0f / sqrtf((float)(acc + 1));  // self-loop => deg >= 1
}

// ---------- 3-phase exclusive scan (N=100k) ----------
__global__ void k_scan1(const int* __restrict__ cnt, int* __restrict__ off,
                        int* __restrict__ bsums, int n) {
  __shared__ int s[256];
  int tid = threadIdx.x;
  int gid = blockIdx.x * 256 + tid;
  int v = (gid < n) ? cnt[gid] : 0;
  s[tid] = v; __syncthreads();
  for (int o = 1; o < 256; o <<= 1) {
    int t = (tid >= o) ? s[tid - o] : 0;
    __syncthreads();
    s[tid] += t;
    __syncthreads();
  }
  if (gid < n) off[gid] = s[tid] - v;
  if (tid == 255) bsums[blockIdx.x] = s[255];
}

__global__ void k_scan2(int* __restrict__ bsums, int nb) {
  __shared__ int s[512];
  int tid = threadIdx.x;
  int v = (tid < nb) ? bsums[tid] : 0;
  s[tid] = v; __syncthreads();
  for (int o = 1; o < 512; o <<= 1) {
    int t = (tid >= o) ? s[tid - o] : 0;
    __syncthreads();
    s[tid] += t;
    __syncthreads();
  }
  if (tid < nb) bsums[tid] = s[tid] - v;
}

__global__ void k_off_final(int* __restrict__ off, const int* __restrict__ bsums,
                            int n, int E) {
  int gid = blockIdx.x * 256 + threadIdx.x;
  if (gid < n) off[gid] += bsums[blockIdx.x];
  if (gid == 0) off[n] = E;
}

// ---------- pass4: colored CSR fill (R4: WRITE_SIZE 105 -> 11.5 MB) ----------
__global__ __launch_bounds__(256) void k_fill_col(const int* __restrict__ src,
                                                  const int* __restrict__ dst,
                                                  const int* __restrict__ off,
                                                  const ushort_t* __restrict__ partial,
                                                  int* __restrict__ csr, int E, int n,
                                                  int rng) {
  extern __shared__ int cur[];
  int color = blockIdx.x & (NCOLOR - 1);
  int sub = blockIdx.x >> 3;
  int base = color * rng;
  int hi = n - base; if (hi > rng) hi = rng;
  const ushort_t* pp = partial + (size_t)blockIdx.x * rng;
  for (int i = threadIdx.x; i < hi; i += 256) cur[i] = off[base + i] + (int)pp[i];
  __syncthreads();
  for (int e = sub * 256 + threadIdx.x; e < E; e += KB * 256) {
    int d = dst[e] - base;
    if ((unsigned)d < (unsigned)hi) {
      int s = src[e];
      int p = atomicAdd(&cur[d], 1);
      csr[p] = s;
    }
  }
}

// ---------- MFMA GEMM: out[n,f] = dinv[n] * (in[n,:K] @ W[:K,:64]), bf16 out ----
// Wave computes a 16-node x 64-feature tile via 16x16x32 bf16 MFMA.
// Verified layouts: A[m=lane&15][k=quad*8+j]; B[k=quad*8+j][nf=lane&15];
// C/D col=lane&15, row=quad*4+reg. B frags (W) preloaded to VGPRs once.
// (R5: the "W column in VGPRs" VALU gemm got VGPR-capped at 68 by the
// allocator, which re-loaded W per node -> 115 us latency-bound.)
template <int K, int INF32>
__global__ __launch_bounds__(256, 2) void k_gemm_mfma(const void* __restrict__ inv,
                                                      const float* __restrict__ Wg,
                                                      const float* __restrict__ dinv,
                                                      bf16* __restrict__ out, int n) {
  constexpr int KS = K / 32;
  int lane = threadIdx.x & 63;
  int quad = lane >> 4;
  int col = lane & 15;  // D column; also A-frag row for this lane

  bf8_t bfrag[4][KS];
#pragma unroll
  for (int c = 0; c < 4; ++c)
#pragma unroll
    for (int s = 0; s < KS; ++s)
#pragma unroll
      for (int j = 0; j < 8; ++j)
        bfrag[c][s][j] = f2bbits(Wg[(s * 32 + quad * 8 + j) * 64 + c * 16 + col]);

  int wid = (blockIdx.x * blockDim.x + threadIdx.x) >> 6;
  int nw = (gridDim.x * blockDim.x) >> 6;
  int tiles = (n + 15) >> 4;
  for (int t = wid; t < tiles; t += nw) {
    int base = t << 4;
    int arow = base + col;
    if (arow >= n) arow = n - 1;

    bf8_t afrag[KS];
    if (INF32) {
      const float* xr = (const float*)inv + (size_t)arow * K;
#pragma unroll
      for (int s = 0; s < KS; ++s) {
        float4 u0 = *(const float4*)(xr + s * 32 + quad * 8);
        float4 u1 = *(const float4*)(xr + s * 32 + quad * 8 + 4);
        afrag[s][0] = f2bbits(u0.x);
        afrag[s][1] = f2bbits(u0.y);
        afrag[s][2] = f2bbits(u0.z);
        afrag[s][3] = f2bbits(u0.w);
        afrag[s][4] = f2bbits(u1.x);
        afrag[s][5] = f2bbits(u1.y);
        afrag[s][6] = f2bbits(u1.z);
        afrag[s][7] = f2bbits(u1.w);
      }
    } else {
      const bf16* xr = (const bf16*)inv + (size_t)arow * K;
#pragma unroll
      for (int s = 0; s < KS; ++s)
        afrag[s] = *(const bf8_t*)(xr + s * 32 + quad * 8);
    }

    f4_t acc[4];
#pragma unroll
    for (int c = 0; c < 4; ++c) acc[c] = (f4_t){0.f, 0.f, 0.f, 0.f};
#pragma unroll
    for (int s = 0; s < KS; ++s)
#pragma unroll
      for (int c = 0; c < 4; ++c)
        acc[c] = __builtin_amdgcn_mfma_f32_16x16x32_bf16(afrag[s], bfrag[c][s],
                                                         acc[c], 0, 0, 0);
#pragma unroll
    for (int r = 0; r < 4; ++r) {
      int row = base + quad * 4 + r;
      if (row < n) {
        float sc = dinv[row];
#pragma unroll
        for (int c = 0; c < 4; ++c)
          out[(size_t)row * 64 + c * 16 + col] = f2b(acc[c][r] * sc);
      }
    }
  }
}

// ---------- aggregate: out[d] = act(dinv[d]*(sum_{s in N(d)} h'[s] + h'[d]) + b)
template <int OUTF32>
__global__ __launch_bounds__(256) void k_agg(const bf16* __restrict__ hp,
                                             const int* __restrict__ off,
                                             const int* __restrict__ csr,
                                             const float* __restrict__ dinv,
                                             const float* __restrict__ bias,
                                             void* __restrict__ outv, int n,
                                             int do_relu) {
  int lane = threadIdx.x & 63;
  int wid = (blockIdx.x * blockDim.x + threadIdx.x) >> 6;
  int nw = (gridDim.x * blockDim.x) >> 6;
  float b = bias[lane];
  for (int node = wid; node < n; node += nw) {
    int un = wave_uniform(node);
    int beg = off[un], end = off[un + 1];
    float acc = b2f(hp[(size_t)un * 64 + lane]);  // self-loop
    int e = beg;
    for (; e + 8 <= end; e += 8) {
      int s0 = csr[e + 0], s1 = csr[e + 1], s2 = csr[e + 2], s3 = csr[e + 3];
      int s4 = csr[e + 4], s5 = csr[e + 5], s6 = csr[e + 6], s7 = csr[e + 7];
      float a0 = b2f(hp[(size_t)s0 * 64 + lane]);
      float a1 = b2f(hp[(size_t)s1 * 64 + lane]);
      float a2 = b2f(hp[(size_t)s2 * 64 + lane]);
      float a3 = b2f(hp[(size_t)s3 * 64 + lane]);
      float a4 = b2f(hp[(size_t)s4 * 64 + lane]);
      float a5 = b2f(hp[(size_t)s5 * 64 + lane]);
      float a6 = b2f(hp[(size_t)s6 * 64 + lane]);
      float a7 = b2f(hp[(size_t)s7 * 64 + lane]);
      acc += ((a0 + a1) + (a2 + a3)) + ((a4 + a5) + (a6 + a7));
    }
    for (; e < end; ++e) acc += b2f(hp[(size_t)csr[e] * 64 + lane]);
    float v = fmaf(acc, dinv[un], b);
    if (do_relu) v = fmaxf(v, 0.f);
    if (OUTF32)
      ((float*)outv)[(size_t)un * 64 + lane] = v;
    else
      ((bf16*)outv)[(size_t)un * 64 + lane] = f2b(v);
  }
}

// ---------- mean-pool: segment-reduce over sorted batch (R2 fix) ----------
__global__ __launch_bounds__(256) void k_pool(const float* __restrict__ x3,
                                              const int* __restrict__ batch,
                                              float* __restrict__ pooled,
                                              float* __restrict__ cnt, int n) {
  int lane = threadIdx.x & 63;
  int wid = (blockIdx.x * blockDim.x + threadIdx.x) >> 6;
  int beg = wid * POOL_CHUNK;
  if (beg >= n) return;
  int end = beg + POOL_CHUNK;
  if (end > n) end = n;

  int cur = wave_uniform(batch[beg]);
  float acc = 0.f;
  int cl = 0;
  int i = beg;
  for (; i + 4 <= end; i += 4) {
    int g0 = wave_uniform(batch[i + 0]);
    int g3 = wave_uniform(batch[i + 3]);
    float a0 = x3[(size_t)(i + 0) * 64 + lane];
    float a1 = x3[(size_t)(i + 1) * 64 + lane];
    float a2 = x3[(size_t)(i + 2) * 64 + lane];
    float a3 = x3[(size_t)(i + 3) * 64 + lane];
    if (g0 == cur && g3 == cur) {
      acc += a0 + a1 + a2 + a3;
      cl += 4;
    } else {
      float av[4] = {a0, a1, a2, a3};
#pragma unroll
      for (int k = 0; k < 4; ++k) {
        int g = wave_uniform(batch[i + k]);
        if (g != cur) {
          atomicAdd(&pooled[cur * 64 + lane], acc);
          if (lane == 0) atomicAdd(&cnt[cur], (float)cl);
          acc = 0.f; cl = 0; cur = g;
        }
        acc += av[k];
        cl += 1;
      }
    }
  }
  for (; i < end; ++i) {
    int g = wave_uniform(batch[i]);
    float a = x3[(size_t)i * 64 + lane];
    if (g != cur) {
      atomicAdd(&pooled[cur * 64 + lane], acc);
      if (lane == 0) atomicAdd(&cnt[cur], (float)cl);
      acc = 0.f; cl = 0; cur = g;
    }
    acc += a;
    cl += 1;
  }
  atomicAdd(&pooled[cur * 64 + lane], acc);
  if (lane == 0) atomicAdd(&cnt[cur], (float)cl);
}

// ---------- head: both 64x64 GEMMs + L2 distance ----------
__global__ void k_final(const float* __restrict__ pooled1, const float* __restrict__ cnt1,
                        const float* __restrict__ pooled2, const float* __restrict__ cnt2,
                        const float* __restrict__ Wlin, const float* __restrict__ blin,
                        float* __restrict__ outp) {
  int g = blockIdx.x;
  int lane = threadIdx.x;  // 64 threads
  float c1 = fmaxf(cnt1[g], 1.f), c2 = fmaxf(cnt2[g], 1.f);
  float p1 = pooled1[g * 64 + lane] / c1;
  float p2 = pooled2[g * 64 + lane] / c2;
  float e1 = blin[lane], e2 = blin[lane];
  for (int j = 0; j < 64; ++j) {
    float w = Wlin[j * 64 + lane];
    e1 = fmaf(__shfl(p1, j), w, e1);
    e2 = fmaf(__shfl(p2, j), w, e2);
  }
  float d = e1 - e2 + PD_EPS;
  float sq = d * d;
  for (int o = 32; o > 0; o >>= 1) sq += __shfl_down(sq, o);
  if (lane == 0) outp[g] = sqrtf(sq);
}

extern "C" void kernel_launch(void* const* d_in, const int* in_sizes, int n_in,
                              void* d_out, int out_size, void* d_ws, size_t ws_size,
                              hipStream_t stream) {
  const float* x1 = (const float*)d_in[0];
  const int* ei1 = (const int*)d_in[1];
  const int* batch1 = (const int*)d_in[2];
  const float* x2 = (const float*)d_in[3];
  const int* ei2 = (const int*)d_in[4];
  const int* batch2 = (const int*)d_in[5];
  const float* W1 = (const float*)d_in[6];
  const float* b1 = (const float*)d_in[7];
  const float* W2 = (const float*)d_in[8];
  const float* b2 = (const float*)d_in[9];
  const float* W3 = (const float*)d_in[10];
  const float* b3 = (const float*)d_in[11];
  const float* Wlin = (const float*)d_in[12];
  const float* blin = (const float*)d_in[13];

  const int N = in_sizes[2];      // 100000
  const int E = in_sizes[1] / 2;  // 1600000
  const int rng = (N + NCOLOR - 1) / NCOLOR;  // nodes per color (12500)

  // workspace carve (~59 MB); partial (768*12500 ushort = 19.2 MB) aliases
  // bufF (25.6 MB): partial dead after k_fill_col, bufF born at agg3.
  char* p = (char*)d_ws;
  auto alloc = [&](size_t bytes) {
    char* r = p;
    p += (bytes + 255) & ~(size_t)255;
    return r;
  };
  int* off = (int*)alloc((size_t)(N + 1) * 4);
  int* cntn = (int*)alloc((size_t)N * 4);
  int* bsums = (int*)alloc(512 * 4);
  float* dinv = (float*)alloc((size_t)N * 4);
  int* csr = (int*)alloc((size_t)E * 4);
  char* unionbuf = alloc((size_t)N * 64 * 4);  // max(partial 19.2MB, bufF 25.6MB)
  ushort_t* partial = (ushort_t*)unionbuf;
  float* bufF = (float*)unionbuf;
  bf16* hpA = (bf16*)alloc((size_t)N * 64 * 2);
  bf16* hpB = (bf16*)alloc((size_t)N * 64 * 2);
  float* pooled1 = (float*)alloc((size_t)NGRAPHS * 64 * 4);
  float* cnt1 = (float*)alloc((size_t)NGRAPHS * 4);
  float* pooled2 = (float*)alloc((size_t)NGRAPHS * 64 * 4);
  float* cnt2 = (float*)alloc((size_t)NGRAPHS * 4);

  const int nbN = (N + 255) / 256;
  const size_t ldsB = (size_t)rng * 4;  // 50 KB dynamic LDS -> 3 blocks/CU

  for (int t = 0; t < 2; ++t) {
    const float* x = t ? x2 : x1;
    const int* src = t ? ei2 : ei1;
    const int* dst = src + E;
    const int* batch = t ? batch2 : batch1;
    float* pooled = t ? pooled2 : pooled1;
    float* cnt = t ? cnt2 : cnt1;

    hipMemsetAsync(pooled, 0, (size_t)NGRAPHS * 64 * 4, stream);
    hipMemsetAsync(cnt, 0, (size_t)NGRAPHS * 4, stream);

    // CSR build: colored, no device atomics; grid 768 = 3 blocks/CU
    k_count_part<<<NCOLOR * KB, 256, ldsB, stream>>>(dst, partial, E, N, rng);
    k_reduce_part<<<nbN, 256, 0, stream>>>(partial, cntn, dinv, N, rng);
    k_scan1<<<nbN, 256, 0, stream>>>(cntn, off, bsums, N);
    k_scan2<<<1, 512, 0, stream>>>(bsums, nbN);
    k_off_final<<<nbN, 256, 0, stream>>>(off, bsums, N, E);
    k_fill_col<<<NCOLOR * KB, 256, ldsB, stream>>>(src, dst, off, partial, csr, E, N,
                                                   rng);

    // layer 1 (MFMA, f32 input converted in-register)
    k_gemm_mfma<128, 1><<<512, 256, 0, stream>>>(x, W1, dinv, hpA, N);
    k_agg<0><<<2048, 256, 0, stream>>>(hpA, off, csr, dinv, b1, hpB, N, 1);
    // layer 2
    k_gemm_mfma<64, 0><<<512, 256, 0, stream>>>(hpB, W2, dinv, hpA, N);
    k_agg<0><<<2048, 256, 0, stream>>>(hpA, off, csr, dinv, b2, hpB, N, 1);
    // layer 3 (no relu), agg writes f32 for pooling
    k_gemm_mfma<64, 0><<<512, 256, 0, stream>>>(hpB, W3, dinv, hpA, N);
    k_agg<1><<<2048, 256, 0, stream>>>(hpA, off, csr, dinv, b3, bufF, N, 0);

    const int poolWaves = (N + POOL_CHUNK - 1) / POOL_CHUNK;
    k_pool<<<(poolWaves + 3) / 4, 256, 0, stream>>>(bufF, batch, pooled, cnt, N);
  }
  k_final<<<NGRAPHS, 64, 0, stream>>>(pooled1, cnt1, pooled2, cnt2, Wlin, blin,
                                      (float*)d_out);
}